// Round 8
// baseline (219.043 us; speedup 1.0000x reference)
//
#include <hip/hip_runtime.h>
#include <type_traits>

#define BATCH 2
#define S_LEN 2048
#define DIM 2048
#define NH 16
#define NKV 4
#define HD 128

typedef _Float16 f16x8 __attribute__((ext_vector_type(8)));
typedef float f32x4 __attribute__((ext_vector_type(4)));
typedef unsigned int u32x4 __attribute__((ext_vector_type(4)));
typedef unsigned short u16x4 __attribute__((ext_vector_type(4)));
typedef unsigned short u16x8 __attribute__((ext_vector_type(8)));

__device__ __forceinline__ unsigned short f2h_bits(float f) {
  _Float16 h = (_Float16)f;
  return __builtin_bit_cast(unsigned short, h);
}
__device__ __forceinline__ float h2f(unsigned short u) {
  return (float)__builtin_bit_cast(_Float16, u);
}
__device__ __forceinline__ f16x8 ld8(const unsigned short* p) {
  u32x4 v = *reinterpret_cast<const u32x4*>(p);
  return __builtin_bit_cast(f16x8, v);
}
__device__ __forceinline__ void gload_lds16(const unsigned short* g, unsigned short* l) {
  __builtin_amdgcn_global_load_lds(
      (const __attribute__((address_space(1))) unsigned int*)g,
      (__attribute__((address_space(3))) unsigned int*)l, 16, 0, 0);
}

#define VMWAIT(n) asm volatile("s_waitcnt vmcnt(" #n ")" ::: "memory")

// ---------------- fp32 -> fp16 convert ----------------
__global__ __launch_bounds__(256) void cvt_f32_f16(const float* __restrict__ in,
                                                   unsigned short* __restrict__ out, int n4) {
  int i = blockIdx.x * 256 + threadIdx.x;
  if (i >= n4) return;
  f32x4 v = *reinterpret_cast<const f32x4*>(in + (long)i * 4);
  u16x4 o;
  o.x = f2h_bits(v.x); o.y = f2h_bits(v.y); o.z = f2h_bits(v.z); o.w = f2h_bits(v.w);
  *reinterpret_cast<u16x4*>(out + (long)i * 4) = o;
}

// ---------------- RoPE tables (fp32) ----------------
__global__ __launch_bounds__(256) void rope_tables(float* __restrict__ c, float* __restrict__ s) {
  int idx = blockIdx.x * 256 + threadIdx.x;
  if (idx >= S_LEN * 16) return;
  int i = idx & 15, t = idx >> 4;
  float inv = exp2f(-(float)i * (13.287712379549449f / 16.0f));
  float f = (float)t * inv;
  c[idx] = cosf(f);
  s[idx] = sinf(f);
}

// ======== pipelined 256-row GEMM (unchanged from round 7) ========
template <int NREP, typename OUT>
__global__ __launch_bounds__(512, 2) void gemm_pl(const unsigned short* __restrict__ A,
                                                  const unsigned short* __restrict__ B,
                                                  OUT* __restrict__ C, int K, int ldc) {
  constexpr int BN = 64 * NREP;
  constexpr int BSH = BN * 32;
  constexpr int TS = 16384 + 2 * BSH;
  __shared__ unsigned short lds[2][TS];
  const int tid = threadIdx.x, lane = tid & 63;
  const int wm = tid >> 8, wn = (tid >> 6) & 3;
  const int rlo = lane & 15, hi = lane >> 4;
  const int m0 = blockIdx.x * 256, n0 = blockIdx.y * BN;
  const int NT = K >> 6;
  const int brow = wn * (16 * NREP);
  const int sA_s = tid >> 2;
  const int pc2 = tid & 3;

  auto aRow = [&](int sig) { return (sig & 63) + ((sig >> 6) & 1) * 128 + (sig >> 7) * 64; };

  auto stageAll = [&](int slot, int k0) {
#pragma unroll
    for (int kk = 0; kk < 2; ++kk)
#pragma unroll
      for (int sh = 0; sh < 2; ++sh) {
        int sig = sh * 128 + sA_s;
        int r = aRow(sig);
        int lc2 = pc2 ^ (sig & 3);
        gload_lds16(A + (long)(m0 + r) * K + k0 + kk * 32 + lc2 * 8,
                    &lds[slot][kk * 8192 + sh * 4096 + tid * 8]);
      }
#pragma unroll
    for (int kk = 0; kk < 2; ++kk)
#pragma unroll
      for (int q = 0; q < (NREP + 1) / 2; ++q) {
        int idx = (q == 0) ? tid : (512 + (tid & 255));
        int r = idx >> 2;
        int lc2 = (idx & 3) ^ (r & 3);
        gload_lds16(B + (long)(n0 + r) * K + k0 + kk * 32 + lc2 * 8,
                    &lds[slot][16384 + kk * BSH + idx * 8]);
      }
  };

  f32x4 acc[8][NREP] = {};

  auto rdA = [&](const unsigned short* As, int kk, int mh, f16x8* af) {
#pragma unroll
    for (int i = 0; i < 4; ++i) {
      int ms = mh * 4 + i;
      int sig = (ms & 3) * 16 + rlo + wm * 64 + (ms >> 2) * 128;
      af[i] = ld8(&As[kk * 8192 + sig * 32 + ((hi ^ (sig & 3)) * 8)]);
    }
  };
  auto rdB = [&](const unsigned short* Bs, int kk, f16x8* bf) {
#pragma unroll
    for (int j = 0; j < NREP; ++j) {
      int r = brow + j * 16 + rlo;
      bf[j] = ld8(&Bs[kk * BSH + r * 32 + ((hi ^ (r & 3)) * 8)]);
    }
  };
  auto mm = [&](const f16x8* af, const f16x8* bf, int mh) {
    __builtin_amdgcn_s_setprio(1);
#pragma unroll
    for (int i = 0; i < 4; ++i)
#pragma unroll
      for (int j = 0; j < NREP; ++j)
        acc[mh * 4 + i][j] =
            __builtin_amdgcn_mfma_f32_16x16x32_f16(af[i], bf[j], acc[mh * 4 + i][j], 0, 0, 0);
    __builtin_amdgcn_s_setprio(0);
  };

  stageAll(0, 0);
  for (int t = 0; t < NT; ++t) {
    const int slot = t & 1;
    const unsigned short* As = &lds[slot][0];
    const unsigned short* Bs = &lds[slot][16384];
    VMWAIT(0);
    __builtin_amdgcn_s_barrier();
    asm volatile("" ::: "memory");
    if (t + 1 < NT) stageAll(slot ^ 1, (t + 1) << 6);
    f16x8 bf0[NREP], bf1[NREP], afE[4], afO[4];
    rdB(Bs, 0, bf0);
    rdA(As, 0, 0, afE);
    rdB(Bs, 1, bf1);
    rdA(As, 1, 0, afO);
    mm(afE, bf0, 0);
    rdA(As, 0, 1, afE);
    mm(afO, bf1, 0);
    rdA(As, 1, 1, afO);
    mm(afE, bf0, 1);
    mm(afO, bf1, 1);
  }

#pragma unroll
  for (int ms = 0; ms < 8; ++ms)
#pragma unroll
    for (int j = 0; j < NREP; ++j) {
      int row = m0 + wm * 128 + ms * 16 + hi * 4;
      int col = n0 + brow + j * 16 + rlo;
#pragma unroll
      for (int r = 0; r < 4; ++r) {
        float v = acc[ms][j][r];
        if constexpr (std::is_same<OUT, float>::value)
          C[(long)(row + r) * ldc + col] = v;
        else
          C[(long)(row + r) * ldc + col] = f2h_bits(v);
      }
    }
}

// ---------------- RMSNorm + RoPE + gain, scatter into Q/K layouts ----------------
__global__ __launch_bounds__(256) void qknorm_rope(const unsigned short* __restrict__ qkv,
                                                   const float* __restrict__ ctab,
                                                   const float* __restrict__ stab,
                                                   const float* __restrict__ qgain,
                                                   unsigned short* __restrict__ Qb,
                                                   unsigned short* __restrict__ Kb) {
  const int lane = threadIdx.x & 63;
  const int row = blockIdx.x * 4 + (threadIdx.x >> 6);
  const int NQROWS = BATCH * S_LEN * NH;
  const unsigned short* src;
  unsigned short* dst;
  int m, hh;
  bool isQ;
  if (row < NQROWS) {
    m = row >> 4; hh = row & 15;
    src = qkv + (long)m * 3072 + hh * HD;
    int b = m >> 11, s = m & (S_LEN - 1);
    dst = Qb + (((long)(b * NH + hh)) * S_LEN + s) * HD;
    isQ = true;
  } else {
    int rk = row - NQROWS;
    m = rk >> 2; hh = rk & 3;
    src = qkv + (long)m * 3072 + 2048 + hh * HD;
    int b = m >> 11, s = m & (S_LEN - 1);
    dst = Kb + (((long)(b * NKV + hh)) * S_LEN + s) * HD;
    isQ = false;
  }
  const int s = m & (S_LEN - 1);
  float x0 = h2f(src[lane]);
  float x1 = h2f(src[lane + 64]);
  float ss = x0 * x0 + x1 * x1;
  ss += __shfl_xor(ss, 1); ss += __shfl_xor(ss, 2); ss += __shfl_xor(ss, 4);
  ss += __shfl_xor(ss, 8); ss += __shfl_xor(ss, 16); ss += __shfl_xor(ss, 32);
  float rn = rsqrtf(ss * (1.0f / 128.0f) + 1.1920929e-07f);
  float n0 = x0 * rn, n1 = x1 * rn;
  float partner = __shfl_xor(n0, 16);
  if (lane < 32) {
    int i = lane & 15;
    float c = ctab[s * 16 + i], sn = stab[s * 16 + i];
    n0 = (lane < 16) ? (n0 * c + partner * sn) : (n0 * c - partner * sn);
  }
  if (isQ) { float g = qgain[hh]; n0 *= g; n1 *= g; }
  dst[lane] = f2h_bits(n0);
  dst[lane + 64] = f2h_bits(n1);
}

// ---------------- V transpose: qkv v-block -> Vt[b][kvh][d][s] ----------------
__global__ __launch_bounds__(256) void vtrans(const unsigned short* __restrict__ qkv,
                                              unsigned short* __restrict__ Vt) {
  int idx = blockIdx.x * 256 + threadIdx.x;
  int d = idx & 127;
  int sc = (idx >> 7) & 255;
  int kvh = (idx >> 15) & 3;
  int b = idx >> 17;
  u16x8 v;
#pragma unroll
  for (int j = 0; j < 8; ++j)
    v[j] = qkv[((long)(b * S_LEN + sc * 8 + j)) * 3072 + 2560 + kvh * HD + d];
  *reinterpret_cast<u16x8*>(Vt + (((long)(b * NKV + kvh)) * HD + d) * S_LEN + sc * 8) = v;
}

// ======== causal GQA attention: 512 blocks x 4 waves — two barrier domains per CU ========
// Block (p,h,b), p in 0..15: q-blocks p and 31-p (64 rows each). Wave w: 16 low + 16 high rows.
// K tile [32 rho][128] (kv permuted at staging, chunk ^= rho&7); V tile [128 d][32]
// (chunk ^= (d>>1)&3). 4 slots (64 KB), stage 2 ahead, counted vmcnt 8/4/0.
#define ATT_C3 ((float)(0.08838834764831845 * (2.0 / 30.0) * 1.4426950408889634))
#define ATT_C4 ((float)(30.0 * 1.4426950408889634))
#define ATT_C5 ((float)(60.0 * 1.4426950408889634))
#define ATT_THR ((float)(8.0 * 1.4426950408889634))

__global__ __launch_bounds__(256, 2) void attn(const unsigned short* __restrict__ Qb,
                                               const unsigned short* __restrict__ Kb,
                                               const unsigned short* __restrict__ Vt,
                                               unsigned short* __restrict__ Yb) {
  __shared__ unsigned short Klds[4][32 * 128];
  __shared__ unsigned short Vlds[4][128 * 32];
  const int tid = threadIdx.x, wid = tid >> 6, lane = tid & 63;
  const int p = blockIdx.x, h = blockIdx.y, b = blockIdx.z;
  const int kvh = h >> 2;
  const int rlo = lane & 15, hi = lane >> 4;
  const int qA0 = p * 64 + wid * 16;
  const int qB0 = (31 - p) * 64 + wid * 16;
  const unsigned short* Kp = Kb + ((long)(b * NKV + kvh)) * S_LEN * HD;
  const unsigned short* Vp = Vt + ((long)(b * NKV + kvh)) * HD * S_LEN;
  const unsigned short* QpA = Qb + (((long)(b * NH + h)) * S_LEN + qA0) * HD;
  const unsigned short* QpB = Qb + (((long)(b * NH + h)) * S_LEN + qB0) * HD;
  f16x8 bqA[4], bqB[4];
#pragma unroll
  for (int dk = 0; dk < 4; ++dk) {
    bqA[dk] = ld8(QpA + rlo * HD + dk * 32 + hi * 8);
    bqB[dk] = ld8(QpB + rlo * HD + dk * 32 + hi * 8);
  }
  const int kx = rlo & 7;
  const int vx = (rlo >> 1) & 3;

  f32x4 accA[8] = {}, accB[8] = {};
  float m2cA = ATT_C4 + 128.0f, m2cB = ATT_C4 + 128.0f;
  float lA = 0.0f, lB = 0.0f;
  const int nt = 2 * (31 - p) + 2;
  const int tAlast = 2 * p + (wid >> 1);
  const int tBlast = 2 * (31 - p) + (wid >> 1);

  // 4 gload_lds per thread per tile; LDS dests linear in idx (dst byte = 16*idx)
  auto stage = [&](int slot, int k0) {
#pragma unroll
    for (int c = 0; c < 2; ++c) {
      int idx = tid + c * 256;
      int rho = idx >> 4;
      int kv = 8 * ((rho >> 2) & 3) + (rho & 3) + 4 * (rho >> 4);
      int sch = (idx & 15) ^ (rho & 7);
      gload_lds16(Kp + (long)(k0 + kv) * HD + sch * 8, &Klds[slot][rho * 128 + (idx & 15) * 8]);
    }
#pragma unroll
    for (int c = 0; c < 2; ++c) {
      int idx = tid + c * 256;
      int vD = idx >> 2;
      int vch = (idx & 3) ^ ((vD >> 1) & 3);
      gload_lds16(Vp + (long)vD * S_LEN + k0 + vch * 8, &Vlds[slot][vD * 32 + (idx & 3) * 8]);
    }
  };

  auto softmax = [&](const f32x4& s0, const f32x4& s1, float& m2c, float& l_run,
                     f32x4* accO, int qrel, bool domask) -> f16x8 {
    float ea[8];
#pragma unroll
    for (int j = 0; j < 8; ++j) {
      float sc = (j < 4) ? s0[j] : s1[j - 4];
      float u = __builtin_amdgcn_exp2f(sc * ATT_C3);
      float rr = __builtin_amdgcn_rcpf(u + 1.0f);
      ea[j] = fmaf(-ATT_C5, rr, m2c);
    }
    if (domask) {
#pragma unroll
      for (int j = 0; j < 8; ++j)
        ea[j] = (8 * hi + j > qrel) ? -1e30f : ea[j];
    }
    float pm = ea[0];
#pragma unroll
    for (int j = 1; j < 8; ++j) pm = fmaxf(pm, ea[j]);
    if (!__all(pm <= ATT_THR)) {
      float red = fmaxf(pm, __shfl_xor(pm, 16));
      red = fmaxf(red, __shfl_xor(red, 32));
      red = fmaxf(red, 0.0f);
      m2c -= red;
      float f = __builtin_amdgcn_exp2f(-red);
      l_run *= f;
#pragma unroll
      for (int dt = 0; dt < 8; ++dt) accO[dt] *= f;
#pragma unroll
      for (int j = 0; j < 8; ++j) ea[j] -= red;
    }
    float pv[8];
#pragma unroll
    for (int j = 0; j < 8; ++j) pv[j] = __builtin_amdgcn_exp2f(ea[j]);
    l_run += ((pv[0] + pv[1]) + (pv[2] + pv[3])) + ((pv[4] + pv[5]) + (pv[6] + pv[7]));
    u32x4 pk;
    pk.x = __builtin_bit_cast(unsigned int, __builtin_amdgcn_cvt_pkrtz(pv[0], pv[1]));
    pk.y = __builtin_bit_cast(unsigned int, __builtin_amdgcn_cvt_pkrtz(pv[2], pv[3]));
    pk.z = __builtin_bit_cast(unsigned int, __builtin_amdgcn_cvt_pkrtz(pv[4], pv[5]));
    pk.w = __builtin_bit_cast(unsigned int, __builtin_amdgcn_cvt_pkrtz(pv[6], pv[7]));
    return __builtin_bit_cast(f16x8, pk);
  };

  stage(0, 0);
  stage(1, 32);
  for (int t = 0; t < nt; ++t) {
    if (t + 2 < nt) {
      stage((t + 2) & 3, (t + 2) * 32);
      VMWAIT(8);
    } else if (t + 1 < nt) {
      VMWAIT(4);
    } else {
      VMWAIT(0);
    }
    __builtin_amdgcn_s_barrier();
    asm volatile("" ::: "memory");
    if (t <= tBlast) {
      const bool doA = (t <= tAlast);
      const unsigned short* Kt = Klds[t & 3];
      const unsigned short* Vl = Vlds[t & 3];
      f16x8 ka0[4], ka1[4];
#pragma unroll
      for (int dk = 0; dk < 4; ++dk) {
        int cp = ((dk * 4 + hi) ^ kx) * 8;
        ka0[dk] = ld8(&Kt[rlo * 128 + cp]);
        ka1[dk] = ld8(&Kt[(16 + rlo) * 128 + cp]);
      }
      f32x4 s0B = {0.f, 0.f, 0.f, 0.f}, s1B = s0B, s0A = s0B, s1A = s0B;
      __builtin_amdgcn_s_setprio(1);
#pragma unroll
      for (int dk = 0; dk < 4; ++dk) {
        s0B = __builtin_amdgcn_mfma_f32_16x16x32_f16(ka0[dk], bqB[dk], s0B, 0, 0, 0);
        s1B = __builtin_amdgcn_mfma_f32_16x16x32_f16(ka1[dk], bqB[dk], s1B, 0, 0, 0);
      }
      if (doA) {
#pragma unroll
        for (int dk = 0; dk < 4; ++dk) {
          s0A = __builtin_amdgcn_mfma_f32_16x16x32_f16(ka0[dk], bqA[dk], s0A, 0, 0, 0);
          s1A = __builtin_amdgcn_mfma_f32_16x16x32_f16(ka1[dk], bqA[dk], s1A, 0, 0, 0);
        }
      }
      __builtin_amdgcn_s_setprio(0);
      f16x8 bpB = softmax(s0B, s1B, m2cB, lB, accB, qB0 + rlo - 32 * t, t == tBlast);
      f16x8 bpA;
      if (doA) bpA = softmax(s0A, s1A, m2cA, lA, accA, qA0 + rlo - 32 * t, t == tAlast);
      __builtin_amdgcn_s_setprio(1);
#pragma unroll
      for (int g = 0; g < 2; ++g) {
        f16x8 av[4];
#pragma unroll
        for (int i = 0; i < 4; ++i) {
          int d = (g * 4 + i) * 16 + rlo;
          av[i] = ld8(&Vl[d * 32 + ((hi ^ vx) * 8)]);
        }
#pragma unroll
        for (int i = 0; i < 4; ++i)
          accB[g * 4 + i] = __builtin_amdgcn_mfma_f32_16x16x32_f16(av[i], bpB, accB[g * 4 + i], 0, 0, 0);
        if (doA) {
#pragma unroll
          for (int i = 0; i < 4; ++i)
            accA[g * 4 + i] = __builtin_amdgcn_mfma_f32_16x16x32_f16(av[i], bpA, accA[g * 4 + i], 0, 0, 0);
        }
      }
      __builtin_amdgcn_s_setprio(0);
    }
  }
  float l1 = lA + __shfl_xor(lA, 16); l1 += __shfl_xor(l1, 32);
  float l2 = lB + __shfl_xor(lB, 16); l2 += __shfl_xor(l2, 32);
  float invA2 = 1.0f / l1, invB2 = 1.0f / l2;
  unsigned short* ypA = Yb + ((long)(b * S_LEN + qA0 + rlo)) * DIM + h * HD + 4 * hi;
  unsigned short* ypB = Yb + ((long)(b * S_LEN + qB0 + rlo)) * DIM + h * HD + 4 * hi;
#pragma unroll
  for (int dt = 0; dt < 8; ++dt) {
    u16x4 oA, oB;
#pragma unroll
    for (int r = 0; r < 4; ++r) {
      oA[r] = f2h_bits(accA[dt][r] * invA2);
      oB[r] = f2h_bits(accB[dt][r] * invB2);
    }
    *reinterpret_cast<u16x4*>(ypA + dt * 16) = oA;
    *reinterpret_cast<u16x4*>(ypB + dt * 16) = oB;
  }
}

extern "C" void kernel_launch(void* const* d_in, const int* in_sizes, int n_in,
                              void* d_out, int out_size, void* d_ws, size_t ws_size,
                              hipStream_t stream) {
  const float* x = (const float*)d_in[0];
  const float* Wq = (const float*)d_in[1];
  const float* Wk = (const float*)d_in[2];
  const float* Wv = (const float*)d_in[3];
  const float* Wp = (const float*)d_in[4];
  const float* qg = (const float*)d_in[5];
  float* out = (float*)d_out;

  char* ws = (char*)d_ws;
  size_t off = 0;
  auto alloc = [&](size_t bytes) {
    char* p = ws + off;
    off += (bytes + 255) & ~(size_t)255;
    return p;
  };
  unsigned short* xb   = (unsigned short*)alloc(8388608ull * 2);
  unsigned short* wqkv = (unsigned short*)alloc(6291456ull * 2);
  unsigned short* wpj  = (unsigned short*)alloc(4194304ull * 2);
  unsigned short* qkv  = (unsigned short*)alloc(4096ull * 3072 * 2);
  unsigned short* Qb   = (unsigned short*)alloc(8388608ull * 2);
  unsigned short* Kb   = (unsigned short*)alloc(2097152ull * 2);
  unsigned short* Vt   = (unsigned short*)alloc(2097152ull * 2);
  unsigned short* Yb   = (unsigned short*)alloc(8388608ull * 2);
  float* ctab = (float*)alloc(32768ull * 4);
  float* stab = (float*)alloc(32768ull * 4);

  auto cvt = [&](const float* src, unsigned short* dst, int n) {
    int n4 = n / 4;
    cvt_f32_f16<<<(n4 + 255) / 256, 256, 0, stream>>>(src, dst, n4);
  };
  cvt(x, xb, 8388608);
  cvt(Wq, wqkv, 4194304);
  cvt(Wk, wqkv + 4194304, 1048576);
  cvt(Wv, wqkv + 5242880, 1048576);
  cvt(Wp, wpj, 4194304);
  rope_tables<<<128, 256, 0, stream>>>(ctab, stab);

  gemm_pl<3, unsigned short><<<dim3(16, 16), 512, 0, stream>>>(xb, wqkv, qkv, 2048, 3072);

  qknorm_rope<<<(BATCH * S_LEN * (NH + NKV)) / 4, 256, 0, stream>>>(qkv, ctab, stab, qg, Qb, Kb);
  vtrans<<<(BATCH * NKV * HD * (S_LEN / 8)) / 256, 256, 0, stream>>>(qkv, Vt);

  attn<<<dim3(16, NH, BATCH), 256, 0, stream>>>(Qb, Kb, Vt, Yb);

  gemm_pl<2, float><<<dim3(16, 16), 512, 0, stream>>>(Yb, wpj, out, 2048, 2048);
}

// Round 9
// 213.207 us; speedup vs baseline: 1.0274x; 1.0274x over previous
//
#include <hip/hip_runtime.h>
#include <type_traits>

#define BATCH 2
#define S_LEN 2048
#define DIM 2048
#define NH 16
#define NKV 4
#define HD 128

typedef _Float16 f16x8 __attribute__((ext_vector_type(8)));
typedef float f32x4 __attribute__((ext_vector_type(4)));
typedef unsigned int u32x4 __attribute__((ext_vector_type(4)));
typedef unsigned short u16x4 __attribute__((ext_vector_type(4)));
typedef unsigned short u16x8 __attribute__((ext_vector_type(8)));

__device__ __forceinline__ unsigned short f2h_bits(float f) {
  _Float16 h = (_Float16)f;
  return __builtin_bit_cast(unsigned short, h);
}
__device__ __forceinline__ float h2f(unsigned short u) {
  return (float)__builtin_bit_cast(_Float16, u);
}
__device__ __forceinline__ f16x8 ld8(const unsigned short* p) {
  u32x4 v = *reinterpret_cast<const u32x4*>(p);
  return __builtin_bit_cast(f16x8, v);
}
__device__ __forceinline__ void gload_lds16(const unsigned short* g, unsigned short* l) {
  __builtin_amdgcn_global_load_lds(
      (const __attribute__((address_space(1))) unsigned int*)g,
      (__attribute__((address_space(3))) unsigned int*)l, 16, 0, 0);
}

#define VMWAIT(n) asm volatile("s_waitcnt vmcnt(" #n ")" ::: "memory")

// ---------------- fp32 -> fp16 convert ----------------
__global__ __launch_bounds__(256) void cvt_f32_f16(const float* __restrict__ in,
                                                   unsigned short* __restrict__ out, int n4) {
  int i = blockIdx.x * 256 + threadIdx.x;
  if (i >= n4) return;
  f32x4 v = *reinterpret_cast<const f32x4*>(in + (long)i * 4);
  u16x4 o;
  o.x = f2h_bits(v.x); o.y = f2h_bits(v.y); o.z = f2h_bits(v.z); o.w = f2h_bits(v.w);
  *reinterpret_cast<u16x4*>(out + (long)i * 4) = o;
}

// ---------------- RoPE tables (fp32) ----------------
__global__ __launch_bounds__(256) void rope_tables(float* __restrict__ c, float* __restrict__ s) {
  int idx = blockIdx.x * 256 + threadIdx.x;
  if (idx >= S_LEN * 16) return;
  int i = idx & 15, t = idx >> 4;
  float inv = exp2f(-(float)i * (13.287712379549449f / 16.0f));
  float f = (float)t * inv;
  c[idx] = cosf(f);
  s[idx] = sinf(f);
}

// ======== pipelined 256-row GEMM (unchanged from round 7) ========
template <int NREP, typename OUT>
__global__ __launch_bounds__(512, 2) void gemm_pl(const unsigned short* __restrict__ A,
                                                  const unsigned short* __restrict__ B,
                                                  OUT* __restrict__ C, int K, int ldc) {
  constexpr int BN = 64 * NREP;
  constexpr int BSH = BN * 32;
  constexpr int TS = 16384 + 2 * BSH;
  __shared__ unsigned short lds[2][TS];
  const int tid = threadIdx.x, lane = tid & 63;
  const int wm = tid >> 8, wn = (tid >> 6) & 3;
  const int rlo = lane & 15, hi = lane >> 4;
  const int m0 = blockIdx.x * 256, n0 = blockIdx.y * BN;
  const int NT = K >> 6;
  const int brow = wn * (16 * NREP);
  const int sA_s = tid >> 2;
  const int pc2 = tid & 3;

  auto aRow = [&](int sig) { return (sig & 63) + ((sig >> 6) & 1) * 128 + (sig >> 7) * 64; };

  auto stageAll = [&](int slot, int k0) {
#pragma unroll
    for (int kk = 0; kk < 2; ++kk)
#pragma unroll
      for (int sh = 0; sh < 2; ++sh) {
        int sig = sh * 128 + sA_s;
        int r = aRow(sig);
        int lc2 = pc2 ^ (sig & 3);
        gload_lds16(A + (long)(m0 + r) * K + k0 + kk * 32 + lc2 * 8,
                    &lds[slot][kk * 8192 + sh * 4096 + tid * 8]);
      }
#pragma unroll
    for (int kk = 0; kk < 2; ++kk)
#pragma unroll
      for (int q = 0; q < (NREP + 1) / 2; ++q) {
        int idx = (q == 0) ? tid : (512 + (tid & 255));
        int r = idx >> 2;
        int lc2 = (idx & 3) ^ (r & 3);
        gload_lds16(B + (long)(n0 + r) * K + k0 + kk * 32 + lc2 * 8,
                    &lds[slot][16384 + kk * BSH + idx * 8]);
      }
  };

  f32x4 acc[8][NREP] = {};

  auto rdA = [&](const unsigned short* As, int kk, int mh, f16x8* af) {
#pragma unroll
    for (int i = 0; i < 4; ++i) {
      int ms = mh * 4 + i;
      int sig = (ms & 3) * 16 + rlo + wm * 64 + (ms >> 2) * 128;
      af[i] = ld8(&As[kk * 8192 + sig * 32 + ((hi ^ (sig & 3)) * 8)]);
    }
  };
  auto rdB = [&](const unsigned short* Bs, int kk, f16x8* bf) {
#pragma unroll
    for (int j = 0; j < NREP; ++j) {
      int r = brow + j * 16 + rlo;
      bf[j] = ld8(&Bs[kk * BSH + r * 32 + ((hi ^ (r & 3)) * 8)]);
    }
  };
  auto mm = [&](const f16x8* af, const f16x8* bf, int mh) {
    __builtin_amdgcn_s_setprio(1);
#pragma unroll
    for (int i = 0; i < 4; ++i)
#pragma unroll
      for (int j = 0; j < NREP; ++j)
        acc[mh * 4 + i][j] =
            __builtin_amdgcn_mfma_f32_16x16x32_f16(af[i], bf[j], acc[mh * 4 + i][j], 0, 0, 0);
    __builtin_amdgcn_s_setprio(0);
  };

  stageAll(0, 0);
  for (int t = 0; t < NT; ++t) {
    const int slot = t & 1;
    const unsigned short* As = &lds[slot][0];
    const unsigned short* Bs = &lds[slot][16384];
    VMWAIT(0);
    __builtin_amdgcn_s_barrier();
    asm volatile("" ::: "memory");
    if (t + 1 < NT) stageAll(slot ^ 1, (t + 1) << 6);
    f16x8 bf0[NREP], bf1[NREP], afE[4], afO[4];
    rdB(Bs, 0, bf0);
    rdA(As, 0, 0, afE);
    rdB(Bs, 1, bf1);
    rdA(As, 1, 0, afO);
    mm(afE, bf0, 0);
    rdA(As, 0, 1, afE);
    mm(afO, bf1, 0);
    rdA(As, 1, 1, afO);
    mm(afE, bf0, 1);
    mm(afO, bf1, 1);
  }

#pragma unroll
  for (int ms = 0; ms < 8; ++ms)
#pragma unroll
    for (int j = 0; j < NREP; ++j) {
      int row = m0 + wm * 128 + ms * 16 + hi * 4;
      int col = n0 + brow + j * 16 + rlo;
#pragma unroll
      for (int r = 0; r < 4; ++r) {
        float v = acc[ms][j][r];
        if constexpr (std::is_same<OUT, float>::value)
          C[(long)(row + r) * ldc + col] = v;
        else
          C[(long)(row + r) * ldc + col] = f2h_bits(v);
      }
    }
}

// ---------------- RMSNorm + RoPE + gain, scatter into Q/K layouts ----------------
__global__ __launch_bounds__(256) void qknorm_rope(const unsigned short* __restrict__ qkv,
                                                   const float* __restrict__ ctab,
                                                   const float* __restrict__ stab,
                                                   const float* __restrict__ qgain,
                                                   unsigned short* __restrict__ Qb,
                                                   unsigned short* __restrict__ Kb) {
  const int lane = threadIdx.x & 63;
  const int row = blockIdx.x * 4 + (threadIdx.x >> 6);
  const int NQROWS = BATCH * S_LEN * NH;
  const unsigned short* src;
  unsigned short* dst;
  int m, hh;
  bool isQ;
  if (row < NQROWS) {
    m = row >> 4; hh = row & 15;
    src = qkv + (long)m * 3072 + hh * HD;
    int b = m >> 11, s = m & (S_LEN - 1);
    dst = Qb + (((long)(b * NH + hh)) * S_LEN + s) * HD;
    isQ = true;
  } else {
    int rk = row - NQROWS;
    m = rk >> 2; hh = rk & 3;
    src = qkv + (long)m * 3072 + 2048 + hh * HD;
    int b = m >> 11, s = m & (S_LEN - 1);
    dst = Kb + (((long)(b * NKV + hh)) * S_LEN + s) * HD;
    isQ = false;
  }
  const int s = m & (S_LEN - 1);
  float x0 = h2f(src[lane]);
  float x1 = h2f(src[lane + 64]);
  float ss = x0 * x0 + x1 * x1;
  ss += __shfl_xor(ss, 1); ss += __shfl_xor(ss, 2); ss += __shfl_xor(ss, 4);
  ss += __shfl_xor(ss, 8); ss += __shfl_xor(ss, 16); ss += __shfl_xor(ss, 32);
  float rn = rsqrtf(ss * (1.0f / 128.0f) + 1.1920929e-07f);
  float n0 = x0 * rn, n1 = x1 * rn;
  float partner = __shfl_xor(n0, 16);
  if (lane < 32) {
    int i = lane & 15;
    float c = ctab[s * 16 + i], sn = stab[s * 16 + i];
    n0 = (lane < 16) ? (n0 * c + partner * sn) : (n0 * c - partner * sn);
  }
  if (isQ) { float g = qgain[hh]; n0 *= g; n1 *= g; }
  dst[lane] = f2h_bits(n0);
  dst[lane + 64] = f2h_bits(n1);
}

// ---------------- V transpose: qkv v-block -> Vt[b][kvh][d][s] ----------------
__global__ __launch_bounds__(256) void vtrans(const unsigned short* __restrict__ qkv,
                                              unsigned short* __restrict__ Vt) {
  int idx = blockIdx.x * 256 + threadIdx.x;
  int d = idx & 127;
  int sc = (idx >> 7) & 255;
  int kvh = (idx >> 15) & 3;
  int b = idx >> 17;
  u16x8 v;
#pragma unroll
  for (int j = 0; j < 8; ++j)
    v[j] = qkv[((long)(b * S_LEN + sc * 8 + j)) * 3072 + 2560 + kvh * HD + d];
  *reinterpret_cast<u16x8*>(Vt + (((long)(b * NKV + kvh)) * HD + d) * S_LEN + sc * 8) = v;
}

// ======== causal GQA attention: 1024 blocks x 4 waves, 16 waves/CU, invariant addressing ========
// Block -> one 64-row q-block (qb from a 4-quarter balance permutation). Wave w: rows
// qb*64 + 16w .. +15. 2 LDS slots (32 KB): K [32 rho][128] (kv-permuted, chunk ^= rho&7),
// V [128 d][32] (chunk ^= (d>>1)&3). Loop hand-unrolled x2 so slot is a literal ->
// all ds_reads are base-VGPR + immediate; staging src pointers increment by constants.
#define ATT_C3 ((float)(0.08838834764831845 * (2.0 / 30.0) * 1.4426950408889634))
#define ATT_C4 ((float)(30.0 * 1.4426950408889634))
#define ATT_C5 ((float)(60.0 * 1.4426950408889634))
#define ATT_THR ((float)(8.0 * 1.4426950408889634))

__global__ __launch_bounds__(256, 4) void attn(const unsigned short* __restrict__ Qb,
                                               const unsigned short* __restrict__ Kb,
                                               const unsigned short* __restrict__ Vt,
                                               unsigned short* __restrict__ Yb) {
  __shared__ unsigned short sm[2][8192];  // per slot: K at [0,4096), V at [4096,8192)
  const int tid = threadIdx.x, wid = tid >> 6, lane = tid & 63;
  // balanced decode: quarters of the grid map to qb groups {j, 23-j, j, 55-j} so the
  // 4 blocks round-robined onto one CU sum to ~constant work
  const int gx = blockIdx.x;
  const int c = gx & 255, qq = gx >> 8;
  const int h = c & 15, b = (c >> 4) & 1;
  const int j = ((c >> 5) & 7) | (qq << 3);
  int qb;
  if (j < 8) qb = j;
  else if (j < 16) qb = 23 - j;
  else if (j < 24) qb = j;
  else qb = 55 - j;

  const int kvh = h >> 2;
  const int rlo = lane & 15, hi = lane >> 4;
  const int q0 = qb * 64 + wid * 16;
  const unsigned short* Kp = Kb + ((long)(b * NKV + kvh)) * S_LEN * HD;
  const unsigned short* Vp = Vt + ((long)(b * NKV + kvh)) * HD * S_LEN;
  const unsigned short* Qp = Qb + (((long)(b * NH + h)) * S_LEN + q0) * HD;
  f16x8 bq[4];
#pragma unroll
  for (int dk = 0; dk < 4; ++dk) bq[dk] = ld8(Qp + rlo * HD + dk * 32 + hi * 8);

  // loop-invariant ds_read base addresses
  const int kx = rlo & 7;
  const int vx = hi ^ ((rlo >> 1) & 3);
  const unsigned short* aK[4];
#pragma unroll
  for (int dk = 0; dk < 4; ++dk) aK[dk] = &sm[0][rlo * 128 + ((dk * 4 + hi) ^ kx) * 8];
  const unsigned short* aV = &sm[0][4096 + rlo * 32 + vx * 8];

  // staging: 2 K-loads + 2 V-loads per thread per tile; src pointers advance by constants
  const int i0 = tid, i1 = tid + 256;
  const int rho0 = i0 >> 4, rho1 = i1 >> 4;
  auto kvperm = [](int r) { return 8 * ((r >> 2) & 3) + (r & 3) + 4 * (r >> 4); };
  const unsigned short* sK0 = Kp + (long)kvperm(rho0) * HD + ((i0 & 15) ^ (rho0 & 7)) * 8;
  const unsigned short* sK1 = Kp + (long)kvperm(rho1) * HD + ((i1 & 15) ^ (rho1 & 7)) * 8;
  const int vd0 = i0 >> 2, vd1 = i1 >> 2;
  const unsigned short* sV0 = Vp + (long)vd0 * S_LEN + ((i0 & 3) ^ ((vd0 >> 1) & 3)) * 8;
  const unsigned short* sV1 = Vp + (long)vd1 * S_LEN + ((i1 & 3) ^ ((vd1 >> 1) & 3)) * 8;
  unsigned short* dK0 = &sm[0][rho0 * 128 + (i0 & 15) * 8];
  unsigned short* dK1 = &sm[0][rho1 * 128 + (i1 & 15) * 8];
  unsigned short* dV0 = &sm[0][4096 + vd0 * 32 + (i0 & 3) * 8];
  unsigned short* dV1 = &sm[0][4096 + vd1 * 32 + (i1 & 3) * 8];

  f32x4 acc[8] = {};
  float m2c = ATT_C4 + 128.0f;
  float l_run = 0.0f;
  const int nt = 2 * qb + 2;                // even
  const int twlast = 2 * qb + (wid >> 1);   // this wave's last tile (mask there)

#define STAGE(SLOT)                                                       \
  {                                                                       \
    gload_lds16(sK0, dK0 + (SLOT)*8192);                                  \
    gload_lds16(sK1, dK1 + (SLOT)*8192);                                  \
    gload_lds16(sV0, dV0 + (SLOT)*8192);                                  \
    gload_lds16(sV1, dV1 + (SLOT)*8192);                                  \
    sK0 += 4096; sK1 += 4096; sV0 += 32; sV1 += 32;                       \
  }

#define COMPUTE(T, SLOT)                                                              \
  {                                                                                   \
    f16x8 ka0[4], ka1[4];                                                             \
    _Pragma("unroll")                                                                 \
    for (int dk = 0; dk < 4; ++dk) {                                                  \
      ka0[dk] = ld8(aK[dk] + (SLOT)*8192);                                            \
      ka1[dk] = ld8(aK[dk] + (SLOT)*8192 + 2048);                                     \
    }                                                                                 \
    f32x4 s0 = {0.f, 0.f, 0.f, 0.f}, s1 = s0;                                         \
    __builtin_amdgcn_s_setprio(1);                                                    \
    _Pragma("unroll")                                                                 \
    for (int dk = 0; dk < 4; ++dk) {                                                  \
      s0 = __builtin_amdgcn_mfma_f32_16x16x32_f16(ka0[dk], bq[dk], s0, 0, 0, 0);      \
      s1 = __builtin_amdgcn_mfma_f32_16x16x32_f16(ka1[dk], bq[dk], s1, 0, 0, 0);      \
    }                                                                                 \
    __builtin_amdgcn_s_setprio(0);                                                    \
    float ea[8];                                                                      \
    _Pragma("unroll")                                                                 \
    for (int jj = 0; jj < 8; ++jj) {                                                  \
      float sc = (jj < 4) ? s0[jj] : s1[jj - 4];                                      \
      float u = __builtin_amdgcn_exp2f(sc * ATT_C3);                                  \
      float rr = __builtin_amdgcn_rcpf(u + 1.0f);                                     \
      ea[jj] = fmaf(-ATT_C5, rr, m2c);                                                \
    }                                                                                 \
    if ((T) == twlast) {                                                              \
      int qrel = q0 + rlo - 32 * (T);                                                 \
      _Pragma("unroll")                                                               \
      for (int jj = 0; jj < 8; ++jj)                                                  \
        ea[jj] = (8 * hi + jj > qrel) ? -1e30f : ea[jj];                              \
    }                                                                                 \
    float pm = ea[0];                                                                 \
    _Pragma("unroll")                                                                 \
    for (int jj = 1; jj < 8; ++jj) pm = fmaxf(pm, ea[jj]);                            \
    if (!__all(pm <= ATT_THR)) {                                                      \
      float red = fmaxf(pm, __shfl_xor(pm, 16));                                      \
      red = fmaxf(red, __shfl_xor(red, 32));                                          \
      red = fmaxf(red, 0.0f);                                                         \
      m2c -= red;                                                                     \
      float ff = __builtin_amdgcn_exp2f(-red);                                        \
      l_run *= ff;                                                                    \
      _Pragma("unroll")                                                               \
      for (int dt = 0; dt < 8; ++dt) acc[dt] *= ff;                                   \
      _Pragma("unroll")                                                               \
      for (int jj = 0; jj < 8; ++jj) ea[jj] -= red;                                   \
    }                                                                                 \
    float pv[8];                                                                      \
    _Pragma("unroll")                                                                 \
    for (int jj = 0; jj < 8; ++jj) pv[jj] = __builtin_amdgcn_exp2f(ea[jj]);           \
    l_run += ((pv[0] + pv[1]) + (pv[2] + pv[3])) + ((pv[4] + pv[5]) + (pv[6] + pv[7]));\
    u32x4 pk;                                                                         \
    pk.x = __builtin_bit_cast(unsigned int, __builtin_amdgcn_cvt_pkrtz(pv[0], pv[1]));\
    pk.y = __builtin_bit_cast(unsigned int, __builtin_amdgcn_cvt_pkrtz(pv[2], pv[3]));\
    pk.z = __builtin_bit_cast(unsigned int, __builtin_amdgcn_cvt_pkrtz(pv[4], pv[5]));\
    pk.w = __builtin_bit_cast(unsigned int, __builtin_amdgcn_cvt_pkrtz(pv[6], pv[7]));\
    f16x8 bp = __builtin_bit_cast(f16x8, pk);                                         \
    __builtin_amdgcn_s_setprio(1);                                                    \
    _Pragma("unroll")                                                                 \
    for (int g = 0; g < 2; ++g) {                                                     \
      f16x8 av[4];                                                                    \
      _Pragma("unroll")                                                               \
      for (int i = 0; i < 4; ++i) av[i] = ld8(aV + (SLOT)*8192 + (g * 4 + i) * 512);  \
      _Pragma("unroll")                                                               \
      for (int i = 0; i < 4; ++i)                                                     \
        acc[g * 4 + i] =                                                              \
            __builtin_amdgcn_mfma_f32_16x16x32_f16(av[i], bp, acc[g * 4 + i], 0, 0, 0);\
    }                                                                                 \
    __builtin_amdgcn_s_setprio(0);                                                    \
  }

  STAGE(0);  // tile 0
  for (int t = 0; t < nt; t += 2) {
    // iter t (slot 0): stage tile t+1 (always exists: nt even, t+1 <= nt-1)
    VMWAIT(0);
    __builtin_amdgcn_s_barrier();
    asm volatile("" ::: "memory");
    STAGE(1);
    if (t <= twlast) COMPUTE(t, 0);
    // iter t+1 (slot 1): stage tile t+2 if it exists
    VMWAIT(0);
    __builtin_amdgcn_s_barrier();
    asm volatile("" ::: "memory");
    if (t + 2 < nt) STAGE(0);
    if (t + 1 <= twlast) COMPUTE(t + 1, 1);
  }
#undef STAGE
#undef COMPUTE

  float l = l_run + __shfl_xor(l_run, 16);
  l += __shfl_xor(l, 32);
  float inv = 1.0f / l;
  unsigned short* yp = Yb + ((long)(b * S_LEN + q0 + rlo)) * DIM + h * HD + 4 * hi;
#pragma unroll
  for (int dt = 0; dt < 8; ++dt) {
    u16x4 o;
#pragma unroll
    for (int r = 0; r < 4; ++r) o[r] = f2h_bits(acc[dt][r] * inv);
    *reinterpret_cast<u16x4*>(yp + dt * 16) = o;
  }
}

extern "C" void kernel_launch(void* const* d_in, const int* in_sizes, int n_in,
                              void* d_out, int out_size, void* d_ws, size_t ws_size,
                              hipStream_t stream) {
  const float* x = (const float*)d_in[0];
  const float* Wq = (const float*)d_in[1];
  const float* Wk = (const float*)d_in[2];
  const float* Wv = (const float*)d_in[3];
  const float* Wp = (const float*)d_in[4];
  const float* qg = (const float*)d_in[5];
  float* out = (float*)d_out;

  char* ws = (char*)d_ws;
  size_t off = 0;
  auto alloc = [&](size_t bytes) {
    char* p = ws + off;
    off += (bytes + 255) & ~(size_t)255;
    return p;
  };
  unsigned short* xb   = (unsigned short*)alloc(8388608ull * 2);
  unsigned short* wqkv = (unsigned short*)alloc(6291456ull * 2);
  unsigned short* wpj  = (unsigned short*)alloc(4194304ull * 2);
  unsigned short* qkv  = (unsigned short*)alloc(4096ull * 3072 * 2);
  unsigned short* Qbuf = (unsigned short*)alloc(8388608ull * 2);
  unsigned short* Kb   = (unsigned short*)alloc(2097152ull * 2);
  unsigned short* Vt   = (unsigned short*)alloc(2097152ull * 2);
  unsigned short* Yb   = (unsigned short*)alloc(8388608ull * 2);
  float* ctab = (float*)alloc(32768ull * 4);
  float* stab = (float*)alloc(32768ull * 4);

  auto cvt = [&](const float* src, unsigned short* dst, int n) {
    int n4 = n / 4;
    cvt_f32_f16<<<(n4 + 255) / 256, 256, 0, stream>>>(src, dst, n4);
  };
  cvt(x, xb, 8388608);
  cvt(Wq, wqkv, 4194304);
  cvt(Wk, wqkv + 4194304, 1048576);
  cvt(Wv, wqkv + 5242880, 1048576);
  cvt(Wp, wpj, 4194304);
  rope_tables<<<128, 256, 0, stream>>>(ctab, stab);

  gemm_pl<3, unsigned short><<<dim3(16, 16), 512, 0, stream>>>(xb, wqkv, qkv, 2048, 3072);

  qknorm_rope<<<(BATCH * S_LEN * (NH + NKV)) / 4, 256, 0, stream>>>(qkv, ctab, stab, qg, Qbuf, Kb);
  vtrans<<<(BATCH * NKV * HD * (S_LEN / 8)) / 256, 256, 0, stream>>>(qkv, Vt);

  attn<<<1024, 256, 0, stream>>>(Qbuf, Kb, Vt, Yb);

  gemm_pl<2, float><<<dim3(16, 16), 512, 0, stream>>>(Yb, wpj, out, 2048, 2048);
}

// Round 10
// 199.903 us; speedup vs baseline: 1.0957x; 1.0666x over previous
//
#include <hip/hip_runtime.h>
#include <type_traits>

#define BATCH 2
#define S_LEN 2048
#define DIM 2048
#define NH 16
#define NKV 4
#define HD 128

typedef _Float16 f16x8 __attribute__((ext_vector_type(8)));
typedef float f32x4 __attribute__((ext_vector_type(4)));
typedef unsigned int u32x4 __attribute__((ext_vector_type(4)));
typedef unsigned short u16x4 __attribute__((ext_vector_type(4)));
typedef unsigned short u16x8 __attribute__((ext_vector_type(8)));

__device__ __forceinline__ unsigned short f2h_bits(float f) {
  _Float16 h = (_Float16)f;
  return __builtin_bit_cast(unsigned short, h);
}
__device__ __forceinline__ float h2f(unsigned short u) {
  return (float)__builtin_bit_cast(_Float16, u);
}
__device__ __forceinline__ f16x8 ld8(const unsigned short* p) {
  u32x4 v = *reinterpret_cast<const u32x4*>(p);
  return __builtin_bit_cast(f16x8, v);
}
__device__ __forceinline__ void gload_lds16(const unsigned short* g, unsigned short* l) {
  __builtin_amdgcn_global_load_lds(
      (const __attribute__((address_space(1))) unsigned int*)g,
      (__attribute__((address_space(3))) unsigned int*)l, 16, 0, 0);
}

#define VMWAIT(n) asm volatile("s_waitcnt vmcnt(" #n ")" ::: "memory")

// ---------------- fused fp32 -> fp16 convert (all 5 tensors, one launch) ----------------
// chunk layout (units of 4 floats): [0,2097152) x->xb | +1048576 Wq->wqkv |
// +262144 Wk->wqkv+4194304 | +262144 Wv->wqkv+5242880 | +1048576 Wp->wpj
__global__ __launch_bounds__(256) void cvt_all(const float* __restrict__ x,
                                               const float* __restrict__ Wq,
                                               const float* __restrict__ Wk,
                                               const float* __restrict__ Wv,
                                               const float* __restrict__ Wp,
                                               unsigned short* __restrict__ xb,
                                               unsigned short* __restrict__ wqkv,
                                               unsigned short* __restrict__ wpj) {
  int i = blockIdx.x * 256 + threadIdx.x;  // 0 .. 4718591
  const float* src;
  unsigned short* dst;
  if (i < 2097152) {
    src = x + (long)i * 4; dst = xb + (long)i * 4;
  } else if (i < 3145728) {
    int k = i - 2097152; src = Wq + (long)k * 4; dst = wqkv + (long)k * 4;
  } else if (i < 3407872) {
    int k = i - 3145728; src = Wk + (long)k * 4; dst = wqkv + 4194304 + (long)k * 4;
  } else if (i < 3670016) {
    int k = i - 3407872; src = Wv + (long)k * 4; dst = wqkv + 5242880 + (long)k * 4;
  } else {
    int k = i - 3670016; src = Wp + (long)k * 4; dst = wpj + (long)k * 4;
  }
  f32x4 v = *reinterpret_cast<const f32x4*>(src);
  u16x4 o;
  o.x = f2h_bits(v.x); o.y = f2h_bits(v.y); o.z = f2h_bits(v.z); o.w = f2h_bits(v.w);
  *reinterpret_cast<u16x4*>(dst) = o;
}

// ---------------- RoPE tables (fp32) ----------------
__global__ __launch_bounds__(256) void rope_tables(float* __restrict__ c, float* __restrict__ s) {
  int idx = blockIdx.x * 256 + threadIdx.x;
  if (idx >= S_LEN * 16) return;
  int i = idx & 15, t = idx >> 4;
  float inv = exp2f(-(float)i * (13.287712379549449f / 16.0f));
  float f = (float)t * inv;
  c[idx] = cosf(f);
  s[idx] = sinf(f);
}

// ======== pipelined 256-row GEMM (unchanged from round 7) ========
template <int NREP, typename OUT>
__global__ __launch_bounds__(512, 2) void gemm_pl(const unsigned short* __restrict__ A,
                                                  const unsigned short* __restrict__ B,
                                                  OUT* __restrict__ C, int K, int ldc) {
  constexpr int BN = 64 * NREP;
  constexpr int BSH = BN * 32;
  constexpr int TS = 16384 + 2 * BSH;
  __shared__ unsigned short lds[2][TS];
  const int tid = threadIdx.x, lane = tid & 63;
  const int wm = tid >> 8, wn = (tid >> 6) & 3;
  const int rlo = lane & 15, hi = lane >> 4;
  const int m0 = blockIdx.x * 256, n0 = blockIdx.y * BN;
  const int NT = K >> 6;
  const int brow = wn * (16 * NREP);
  const int sA_s = tid >> 2;
  const int pc2 = tid & 3;

  auto aRow = [&](int sig) { return (sig & 63) + ((sig >> 6) & 1) * 128 + (sig >> 7) * 64; };

  auto stageAll = [&](int slot, int k0) {
#pragma unroll
    for (int kk = 0; kk < 2; ++kk)
#pragma unroll
      for (int sh = 0; sh < 2; ++sh) {
        int sig = sh * 128 + sA_s;
        int r = aRow(sig);
        int lc2 = pc2 ^ (sig & 3);
        gload_lds16(A + (long)(m0 + r) * K + k0 + kk * 32 + lc2 * 8,
                    &lds[slot][kk * 8192 + sh * 4096 + tid * 8]);
      }
#pragma unroll
    for (int kk = 0; kk < 2; ++kk)
#pragma unroll
      for (int q = 0; q < (NREP + 1) / 2; ++q) {
        int idx = (q == 0) ? tid : (512 + (tid & 255));
        int r = idx >> 2;
        int lc2 = (idx & 3) ^ (r & 3);
        gload_lds16(B + (long)(n0 + r) * K + k0 + kk * 32 + lc2 * 8,
                    &lds[slot][16384 + kk * BSH + idx * 8]);
      }
  };

  f32x4 acc[8][NREP] = {};

  auto rdA = [&](const unsigned short* As, int kk, int mh, f16x8* af) {
#pragma unroll
    for (int i = 0; i < 4; ++i) {
      int ms = mh * 4 + i;
      int sig = (ms & 3) * 16 + rlo + wm * 64 + (ms >> 2) * 128;
      af[i] = ld8(&As[kk * 8192 + sig * 32 + ((hi ^ (sig & 3)) * 8)]);
    }
  };
  auto rdB = [&](const unsigned short* Bs, int kk, f16x8* bf) {
#pragma unroll
    for (int j = 0; j < NREP; ++j) {
      int r = brow + j * 16 + rlo;
      bf[j] = ld8(&Bs[kk * BSH + r * 32 + ((hi ^ (r & 3)) * 8)]);
    }
  };
  auto mm = [&](const f16x8* af, const f16x8* bf, int mh) {
    __builtin_amdgcn_s_setprio(1);
#pragma unroll
    for (int i = 0; i < 4; ++i)
#pragma unroll
      for (int j = 0; j < NREP; ++j)
        acc[mh * 4 + i][j] =
            __builtin_amdgcn_mfma_f32_16x16x32_f16(af[i], bf[j], acc[mh * 4 + i][j], 0, 0, 0);
    __builtin_amdgcn_s_setprio(0);
  };

  stageAll(0, 0);
  for (int t = 0; t < NT; ++t) {
    const int slot = t & 1;
    const unsigned short* As = &lds[slot][0];
    const unsigned short* Bs = &lds[slot][16384];
    VMWAIT(0);
    __builtin_amdgcn_s_barrier();
    asm volatile("" ::: "memory");
    if (t + 1 < NT) stageAll(slot ^ 1, (t + 1) << 6);
    f16x8 bf0[NREP], bf1[NREP], afE[4], afO[4];
    rdB(Bs, 0, bf0);
    rdA(As, 0, 0, afE);
    rdB(Bs, 1, bf1);
    rdA(As, 1, 0, afO);
    mm(afE, bf0, 0);
    rdA(As, 0, 1, afE);
    mm(afO, bf1, 0);
    rdA(As, 1, 1, afO);
    mm(afE, bf0, 1);
    mm(afO, bf1, 1);
  }

#pragma unroll
  for (int ms = 0; ms < 8; ++ms)
#pragma unroll
    for (int j = 0; j < NREP; ++j) {
      int row = m0 + wm * 128 + ms * 16 + hi * 4;
      int col = n0 + brow + j * 16 + rlo;
#pragma unroll
      for (int r = 0; r < 4; ++r) {
        float v = acc[ms][j][r];
        if constexpr (std::is_same<OUT, float>::value)
          C[(long)(row + r) * ldc + col] = v;
        else
          C[(long)(row + r) * ldc + col] = f2h_bits(v);
      }
    }
}

// ---------------- RMSNorm + RoPE + gain, scatter into Q/K layouts ----------------
__global__ __launch_bounds__(256) void qknorm_rope(const unsigned short* __restrict__ qkv,
                                                   const float* __restrict__ ctab,
                                                   const float* __restrict__ stab,
                                                   const float* __restrict__ qgain,
                                                   unsigned short* __restrict__ Qb,
                                                   unsigned short* __restrict__ Kb) {
  const int lane = threadIdx.x & 63;
  const int row = blockIdx.x * 4 + (threadIdx.x >> 6);
  const int NQROWS = BATCH * S_LEN * NH;
  const unsigned short* src;
  unsigned short* dst;
  int m, hh;
  bool isQ;
  if (row < NQROWS) {
    m = row >> 4; hh = row & 15;
    src = qkv + (long)m * 3072 + hh * HD;
    int b = m >> 11, s = m & (S_LEN - 1);
    dst = Qb + (((long)(b * NH + hh)) * S_LEN + s) * HD;
    isQ = true;
  } else {
    int rk = row - NQROWS;
    m = rk >> 2; hh = rk & 3;
    src = qkv + (long)m * 3072 + 2048 + hh * HD;
    int b = m >> 11, s = m & (S_LEN - 1);
    dst = Kb + (((long)(b * NKV + hh)) * S_LEN + s) * HD;
    isQ = false;
  }
  const int s = m & (S_LEN - 1);
  float x0 = h2f(src[lane]);
  float x1 = h2f(src[lane + 64]);
  float ss = x0 * x0 + x1 * x1;
  ss += __shfl_xor(ss, 1); ss += __shfl_xor(ss, 2); ss += __shfl_xor(ss, 4);
  ss += __shfl_xor(ss, 8); ss += __shfl_xor(ss, 16); ss += __shfl_xor(ss, 32);
  float rn = rsqrtf(ss * (1.0f / 128.0f) + 1.1920929e-07f);
  float n0 = x0 * rn, n1 = x1 * rn;
  float partner = __shfl_xor(n0, 16);
  if (lane < 32) {
    int i = lane & 15;
    float c = ctab[s * 16 + i], sn = stab[s * 16 + i];
    n0 = (lane < 16) ? (n0 * c + partner * sn) : (n0 * c - partner * sn);
  }
  if (isQ) { float g = qgain[hh]; n0 *= g; n1 *= g; }
  dst[lane] = f2h_bits(n0);
  dst[lane + 64] = f2h_bits(n1);
}

// ---------------- V transpose: qkv v-block -> Vt[b][kvh][d][s] ----------------
__global__ __launch_bounds__(256) void vtrans(const unsigned short* __restrict__ qkv,
                                              unsigned short* __restrict__ Vt) {
  int idx = blockIdx.x * 256 + threadIdx.x;
  int d = idx & 127;
  int sc = (idx >> 7) & 255;
  int kvh = (idx >> 15) & 3;
  int b = idx >> 17;
  u16x8 v;
#pragma unroll
  for (int j = 0; j < 8; ++j)
    v[j] = qkv[((long)(b * S_LEN + sc * 8 + j)) * 3072 + 2560 + kvh * HD + d];
  *reinterpret_cast<u16x8*>(Vt + (((long)(b * NKV + kvh)) * HD + d) * S_LEN + sc * 8) = v;
}

// ======== causal GQA attention: 1024 blocks x 4 waves, heavy-first dispatch ========
// Quarter qq of the grid -> qb: qq0: 31-a (heaviest FIRST), qq1: 16+a, qq2: 15-a,
// qq3: a (light last = tiny tail). Per-slot 4-deep CU sum = 62 for every a.
// 2 LDS slots (32 KB): K [32 rho][128] (kv-permuted, chunk ^= rho&7), V [128 d][32]
// (chunk ^= (d>>1)&3). Loop unrolled x2 -> slot literal, invariant addressing.
#define ATT_C3 ((float)(0.08838834764831845 * (2.0 / 30.0) * 1.4426950408889634))
#define ATT_C4 ((float)(30.0 * 1.4426950408889634))
#define ATT_C5 ((float)(60.0 * 1.4426950408889634))
#define ATT_THR ((float)(8.0 * 1.4426950408889634))

__global__ __launch_bounds__(256, 4) void attn(const unsigned short* __restrict__ Qb,
                                               const unsigned short* __restrict__ Kb,
                                               const unsigned short* __restrict__ Vt,
                                               unsigned short* __restrict__ Yb) {
  __shared__ unsigned short sm[2][8192];  // per slot: K at [0,4096), V at [4096,8192)
  const int tid = threadIdx.x, wid = tid >> 6, lane = tid & 63;
  const int gx = blockIdx.x;
  const int qq = gx >> 8;
  const int a = (gx >> 5) & 7;
  const int h = gx & 15, b = (gx >> 4) & 1;
  int qb;
  if (qq == 0) qb = 31 - a;
  else if (qq == 1) qb = 16 + a;
  else if (qq == 2) qb = 15 - a;
  else qb = a;

  const int kvh = h >> 2;
  const int rlo = lane & 15, hi = lane >> 4;
  const int q0 = qb * 64 + wid * 16;
  const unsigned short* Kp = Kb + ((long)(b * NKV + kvh)) * S_LEN * HD;
  const unsigned short* Vp = Vt + ((long)(b * NKV + kvh)) * HD * S_LEN;
  const unsigned short* Qp = Qb + (((long)(b * NH + h)) * S_LEN + q0) * HD;
  f16x8 bq[4];
#pragma unroll
  for (int dk = 0; dk < 4; ++dk) bq[dk] = ld8(Qp + rlo * HD + dk * 32 + hi * 8);

  const int kx = rlo & 7;
  const int vx = hi ^ ((rlo >> 1) & 3);
  const unsigned short* aK[4];
#pragma unroll
  for (int dk = 0; dk < 4; ++dk) aK[dk] = &sm[0][rlo * 128 + ((dk * 4 + hi) ^ kx) * 8];
  const unsigned short* aV = &sm[0][4096 + rlo * 32 + vx * 8];

  const int i0 = tid, i1 = tid + 256;
  const int rho0 = i0 >> 4, rho1 = i1 >> 4;
  auto kvperm = [](int r) { return 8 * ((r >> 2) & 3) + (r & 3) + 4 * (r >> 4); };
  const unsigned short* sK0 = Kp + (long)kvperm(rho0) * HD + ((i0 & 15) ^ (rho0 & 7)) * 8;
  const unsigned short* sK1 = Kp + (long)kvperm(rho1) * HD + ((i1 & 15) ^ (rho1 & 7)) * 8;
  const int vd0 = i0 >> 2, vd1 = i1 >> 2;
  const unsigned short* sV0 = Vp + (long)vd0 * S_LEN + ((i0 & 3) ^ ((vd0 >> 1) & 3)) * 8;
  const unsigned short* sV1 = Vp + (long)vd1 * S_LEN + ((i1 & 3) ^ ((vd1 >> 1) & 3)) * 8;
  unsigned short* dK0 = &sm[0][rho0 * 128 + (i0 & 15) * 8];
  unsigned short* dK1 = &sm[0][rho1 * 128 + (i1 & 15) * 8];
  unsigned short* dV0 = &sm[0][4096 + vd0 * 32 + (i0 & 3) * 8];
  unsigned short* dV1 = &sm[0][4096 + vd1 * 32 + (i1 & 3) * 8];

  f32x4 acc[8] = {};
  float m2c = ATT_C4 + 128.0f;
  float l_run = 0.0f;
  const int nt = 2 * qb + 2;                // even
  const int twlast = 2 * qb + (wid >> 1);   // this wave's last tile (mask there)

#define STAGE(SLOT)                                                       \
  {                                                                       \
    gload_lds16(sK0, dK0 + (SLOT)*8192);                                  \
    gload_lds16(sK1, dK1 + (SLOT)*8192);                                  \
    gload_lds16(sV0, dV0 + (SLOT)*8192);                                  \
    gload_lds16(sV1, dV1 + (SLOT)*8192);                                  \
    sK0 += 4096; sK1 += 4096; sV0 += 32; sV1 += 32;                       \
  }

#define COMPUTE(T, SLOT)                                                              \
  {                                                                                   \
    f16x8 ka0[4], ka1[4];                                                             \
    _Pragma("unroll")                                                                 \
    for (int dk = 0; dk < 4; ++dk) {                                                  \
      ka0[dk] = ld8(aK[dk] + (SLOT)*8192);                                            \
      ka1[dk] = ld8(aK[dk] + (SLOT)*8192 + 2048);                                     \
    }                                                                                 \
    f32x4 s0 = {0.f, 0.f, 0.f, 0.f}, s1 = s0;                                         \
    __builtin_amdgcn_s_setprio(1);                                                    \
    _Pragma("unroll")                                                                 \
    for (int dk = 0; dk < 4; ++dk) {                                                  \
      s0 = __builtin_amdgcn_mfma_f32_16x16x32_f16(ka0[dk], bq[dk], s0, 0, 0, 0);      \
      s1 = __builtin_amdgcn_mfma_f32_16x16x32_f16(ka1[dk], bq[dk], s1, 0, 0, 0);      \
    }                                                                                 \
    __builtin_amdgcn_s_setprio(0);                                                    \
    float ea[8];                                                                      \
    _Pragma("unroll")                                                                 \
    for (int jj = 0; jj < 8; ++jj) {                                                  \
      float sc = (jj < 4) ? s0[jj] : s1[jj - 4];                                      \
      float u = __builtin_amdgcn_exp2f(sc * ATT_C3);                                  \
      float rr = __builtin_amdgcn_rcpf(u + 1.0f);                                     \
      ea[jj] = fmaf(-ATT_C5, rr, m2c);                                                \
    }                                                                                 \
    if ((T) == twlast) {                                                              \
      int qrel = q0 + rlo - 32 * (T);                                                 \
      _Pragma("unroll")                                                               \
      for (int jj = 0; jj < 8; ++jj)                                                  \
        ea[jj] = (8 * hi + jj > qrel) ? -1e30f : ea[jj];                              \
    }                                                                                 \
    float pm = ea[0];                                                                 \
    _Pragma("unroll")                                                                 \
    for (int jj = 1; jj < 8; ++jj) pm = fmaxf(pm, ea[jj]);                            \
    if (!__all(pm <= ATT_THR)) {                                                      \
      float red = fmaxf(pm, __shfl_xor(pm, 16));                                      \
      red = fmaxf(red, __shfl_xor(red, 32));                                          \
      red = fmaxf(red, 0.0f);                                                         \
      m2c -= red;                                                                     \
      float ff = __builtin_amdgcn_exp2f(-red);                                        \
      l_run *= ff;                                                                    \
      _Pragma("unroll")                                                               \
      for (int dt = 0; dt < 8; ++dt) acc[dt] *= ff;                                   \
      _Pragma("unroll")                                                               \
      for (int jj = 0; jj < 8; ++jj) ea[jj] -= red;                                   \
    }                                                                                 \
    float pv[8];                                                                      \
    _Pragma("unroll")                                                                 \
    for (int jj = 0; jj < 8; ++jj) pv[jj] = __builtin_amdgcn_exp2f(ea[jj]);           \
    l_run += ((pv[0] + pv[1]) + (pv[2] + pv[3])) + ((pv[4] + pv[5]) + (pv[6] + pv[7]));\
    u32x4 pk;                                                                         \
    pk.x = __builtin_bit_cast(unsigned int, __builtin_amdgcn_cvt_pkrtz(pv[0], pv[1]));\
    pk.y = __builtin_bit_cast(unsigned int, __builtin_amdgcn_cvt_pkrtz(pv[2], pv[3]));\
    pk.z = __builtin_bit_cast(unsigned int, __builtin_amdgcn_cvt_pkrtz(pv[4], pv[5]));\
    pk.w = __builtin_bit_cast(unsigned int, __builtin_amdgcn_cvt_pkrtz(pv[6], pv[7]));\
    f16x8 bp = __builtin_bit_cast(f16x8, pk);                                         \
    __builtin_amdgcn_s_setprio(1);                                                    \
    _Pragma("unroll")                                                                 \
    for (int g = 0; g < 2; ++g) {                                                     \
      f16x8 av[4];                                                                    \
      _Pragma("unroll")                                                               \
      for (int i = 0; i < 4; ++i) av[i] = ld8(aV + (SLOT)*8192 + (g * 4 + i) * 512);  \
      _Pragma("unroll")                                                               \
      for (int i = 0; i < 4; ++i)                                                     \
        acc[g * 4 + i] =                                                              \
            __builtin_amdgcn_mfma_f32_16x16x32_f16(av[i], bp, acc[g * 4 + i], 0, 0, 0);\
    }                                                                                 \
    __builtin_amdgcn_s_setprio(0);                                                    \
  }

  STAGE(0);  // tile 0
  for (int t = 0; t < nt; t += 2) {
    VMWAIT(0);
    __builtin_amdgcn_s_barrier();
    asm volatile("" ::: "memory");
    STAGE(1);
    if (t <= twlast) COMPUTE(t, 0);
    VMWAIT(0);
    __builtin_amdgcn_s_barrier();
    asm volatile("" ::: "memory");
    if (t + 2 < nt) STAGE(0);
    if (t + 1 <= twlast) COMPUTE(t + 1, 1);
  }
#undef STAGE
#undef COMPUTE

  float l = l_run + __shfl_xor(l_run, 16);
  l += __shfl_xor(l, 32);
  float inv = 1.0f / l;
  unsigned short* yp = Yb + ((long)(b * S_LEN + q0 + rlo)) * DIM + h * HD + 4 * hi;
#pragma unroll
  for (int dt = 0; dt < 8; ++dt) {
    u16x4 o;
#pragma unroll
    for (int r = 0; r < 4; ++r) o[r] = f2h_bits(acc[dt][r] * inv);
    *reinterpret_cast<u16x4*>(yp + dt * 16) = o;
  }
}

extern "C" void kernel_launch(void* const* d_in, const int* in_sizes, int n_in,
                              void* d_out, int out_size, void* d_ws, size_t ws_size,
                              hipStream_t stream) {
  const float* x = (const float*)d_in[0];
  const float* Wq = (const float*)d_in[1];
  const float* Wk = (const float*)d_in[2];
  const float* Wv = (const float*)d_in[3];
  const float* Wp = (const float*)d_in[4];
  const float* qg = (const float*)d_in[5];
  float* out = (float*)d_out;

  char* ws = (char*)d_ws;
  size_t off = 0;
  auto alloc = [&](size_t bytes) {
    char* p = ws + off;
    off += (bytes + 255) & ~(size_t)255;
    return p;
  };
  unsigned short* xb   = (unsigned short*)alloc(8388608ull * 2);
  unsigned short* wqkv = (unsigned short*)alloc(6291456ull * 2);
  unsigned short* wpj  = (unsigned short*)alloc(4194304ull * 2);
  unsigned short* qkv  = (unsigned short*)alloc(4096ull * 3072 * 2);
  unsigned short* Qbuf = (unsigned short*)alloc(8388608ull * 2);
  unsigned short* Kb   = (unsigned short*)alloc(2097152ull * 2);
  unsigned short* Vt   = (unsigned short*)alloc(2097152ull * 2);
  unsigned short* Yb   = (unsigned short*)alloc(8388608ull * 2);
  float* ctab = (float*)alloc(32768ull * 4);
  float* stab = (float*)alloc(32768ull * 4);

  cvt_all<<<18432, 256, 0, stream>>>(x, Wq, Wk, Wv, Wp, xb, wqkv, wpj);
  rope_tables<<<128, 256, 0, stream>>>(ctab, stab);

  gemm_pl<3, unsigned short><<<dim3(16, 16), 512, 0, stream>>>(xb, wqkv, qkv, 2048, 3072);

  qknorm_rope<<<(BATCH * S_LEN * (NH + NKV)) / 4, 256, 0, stream>>>(qkv, ctab, stab, qg, Qbuf, Kb);
  vtrans<<<(BATCH * NKV * HD * (S_LEN / 8)) / 256, 256, 0, stream>>>(qkv, Vt);

  attn<<<1024, 256, 0, stream>>>(Qbuf, Kb, Vt, Yb);

  gemm_pl<2, float><<<dim3(16, 16), 512, 0, stream>>>(Yb, wpj, out, 2048, 2048);
}

// Round 11
// 195.789 us; speedup vs baseline: 1.1188x; 1.0210x over previous
//
#include <hip/hip_runtime.h>
#include <type_traits>

#define BATCH 2
#define S_LEN 2048
#define DIM 2048
#define NH 16
#define NKV 4
#define HD 128

typedef _Float16 f16x8 __attribute__((ext_vector_type(8)));
typedef float f32x4 __attribute__((ext_vector_type(4)));
typedef unsigned int u32x4 __attribute__((ext_vector_type(4)));
typedef unsigned short u16x4 __attribute__((ext_vector_type(4)));
typedef unsigned short u16x8 __attribute__((ext_vector_type(8)));

__device__ __forceinline__ unsigned short f2h_bits(float f) {
  _Float16 h = (_Float16)f;
  return __builtin_bit_cast(unsigned short, h);
}
__device__ __forceinline__ float h2f(unsigned short u) {
  return (float)__builtin_bit_cast(_Float16, u);
}
__device__ __forceinline__ f16x8 ld8(const unsigned short* p) {
  u32x4 v = *reinterpret_cast<const u32x4*>(p);
  return __builtin_bit_cast(f16x8, v);
}
__device__ __forceinline__ void gload_lds16(const unsigned short* g, unsigned short* l) {
  __builtin_amdgcn_global_load_lds(
      (const __attribute__((address_space(1))) unsigned int*)g,
      (__attribute__((address_space(3))) unsigned int*)l, 16, 0, 0);
}

#define VMWAIT(n) asm volatile("s_waitcnt vmcnt(" #n ")" ::: "memory")

// ---------------- fused fp32 -> fp16 convert (all 5 tensors, one launch) ----------------
__global__ __launch_bounds__(256) void cvt_all(const float* __restrict__ x,
                                               const float* __restrict__ Wq,
                                               const float* __restrict__ Wk,
                                               const float* __restrict__ Wv,
                                               const float* __restrict__ Wp,
                                               unsigned short* __restrict__ xb,
                                               unsigned short* __restrict__ wqkv,
                                               unsigned short* __restrict__ wpj) {
  int i = blockIdx.x * 256 + threadIdx.x;  // 0 .. 4718591
  const float* src;
  unsigned short* dst;
  if (i < 2097152) {
    src = x + (long)i * 4; dst = xb + (long)i * 4;
  } else if (i < 3145728) {
    int k = i - 2097152; src = Wq + (long)k * 4; dst = wqkv + (long)k * 4;
  } else if (i < 3407872) {
    int k = i - 3145728; src = Wk + (long)k * 4; dst = wqkv + 4194304 + (long)k * 4;
  } else if (i < 3670016) {
    int k = i - 3407872; src = Wv + (long)k * 4; dst = wqkv + 5242880 + (long)k * 4;
  } else {
    int k = i - 3670016; src = Wp + (long)k * 4; dst = wpj + (long)k * 4;
  }
  f32x4 v = *reinterpret_cast<const f32x4*>(src);
  u16x4 o;
  o.x = f2h_bits(v.x); o.y = f2h_bits(v.y); o.z = f2h_bits(v.z); o.w = f2h_bits(v.w);
  *reinterpret_cast<u16x4*>(dst) = o;
}

// ---------------- RoPE tables (fp32) ----------------
__global__ __launch_bounds__(256) void rope_tables(float* __restrict__ c, float* __restrict__ s) {
  int idx = blockIdx.x * 256 + threadIdx.x;
  if (idx >= S_LEN * 16) return;
  int i = idx & 15, t = idx >> 4;
  float inv = exp2f(-(float)i * (13.287712379549449f / 16.0f));
  float f = (float)t * inv;
  c[idx] = cosf(f);
  s[idx] = sinf(f);
}

// ======== GEMM: BK=32, 4 LDS slots, stage-2-ahead, counted vmcnt ========
// BM=256, BN=64*NREP. 512 thr = 8 waves (2M x 4N); per-wave out 128 x 16*NREP.
// Slot: A[sig 0..255][32] (sig quarter-permuted via aRow) + B[r][32] at +8192.
// Chunk swizzle pc = lc ^ ((row>>1)&3): read-octet granules = 4*(row&1)+((row>>1)&3)
// cover all 8 16B bank-groups -> conflict-free ds_read_b128.
// Loop: {vmcnt(LPS) [drains tile t, leaves t+1 in flight]; barrier; stage(t+2); compute(t)}.
// Issue-to-use = 2 tiles; vmcnt(0) only at t=NT-1.
template <int NREP, typename OUT>
__global__ __launch_bounds__(512, 2) void gemm_pl(const unsigned short* __restrict__ A,
                                                  const unsigned short* __restrict__ B,
                                                  OUT* __restrict__ C, int K, int ldc) {
  constexpr int BN = 64 * NREP;
  constexpr int BSH = BN * 32;        // B shorts per slot
  constexpr int TS = 8192 + BSH;      // shorts per slot
  __shared__ unsigned short lds[4][TS];
  const int tid = threadIdx.x, lane = tid & 63;
  const int wm = tid >> 8, wn = (tid >> 6) & 3;
  const int rlo = lane & 15, hi = lane >> 4;
  const int m0 = blockIdx.x * 256, n0 = blockIdx.y * BN;
  const int NT = K >> 5;
  const int brow = wn * (16 * NREP);

  auto aRow = [&](int sig) { return (sig & 63) + ((sig >> 6) & 1) * 128 + (sig >> 7) * 64; };

  // persistent staging source pointers (advance 32 shorts per stage call)
  const int sigA0 = tid >> 2, sigA1 = 128 + (tid >> 2);
  const unsigned short* pA0 =
      A + (long)(m0 + aRow(sigA0)) * K + (((tid & 3) ^ ((sigA0 >> 1) & 3)) * 8);
  const unsigned short* pA1 =
      A + (long)(m0 + aRow(sigA1)) * K + (((tid & 3) ^ ((sigA1 >> 1) & 3)) * 8);
  const int rB0 = tid >> 2;
  const unsigned short* pB0 = B + (long)(n0 + rB0) * K + (((tid & 3) ^ ((rB0 >> 1) & 3)) * 8);
  const int idx1 = 512 + (tid & 255);  // NREP=3 second B half; waves 4-7 duplicate 0-3
  const int rB1 = idx1 >> 2;
  const unsigned short* pB1 = B + (long)(n0 + rB1) * K + (((idx1 & 3) ^ ((rB1 >> 1) & 3)) * 8);

  auto stage = [&](int slot) {
    gload_lds16(pA0, &lds[slot][tid * 8]);
    gload_lds16(pA1, &lds[slot][4096 + tid * 8]);
    gload_lds16(pB0, &lds[slot][8192 + tid * 8]);
    if constexpr (NREP == 3) gload_lds16(pB1, &lds[slot][8192 + idx1 * 8]);
    pA0 += 32; pA1 += 32; pB0 += 32;
    if constexpr (NREP == 3) pB1 += 32;
  };

  f32x4 acc[8][NREP] = {};

  auto rdA = [&](const unsigned short* As, int mh, f16x8* af) {
#pragma unroll
    for (int i = 0; i < 4; ++i) {
      int ms = mh * 4 + i;
      int sig = (ms & 3) * 16 + rlo + wm * 64 + (ms >> 2) * 128;
      af[i] = ld8(&As[sig * 32 + ((hi ^ ((sig >> 1) & 3)) * 8)]);
    }
  };
  auto rdB = [&](const unsigned short* Bs, f16x8* bf) {
#pragma unroll
    for (int j = 0; j < NREP; ++j) {
      int r = brow + j * 16 + rlo;
      bf[j] = ld8(&Bs[r * 32 + ((hi ^ ((r >> 1) & 3)) * 8)]);
    }
  };
  auto mm = [&](const f16x8* af, const f16x8* bf, int mh) {
    __builtin_amdgcn_s_setprio(1);
#pragma unroll
    for (int i = 0; i < 4; ++i)
#pragma unroll
      for (int j = 0; j < NREP; ++j)
        acc[mh * 4 + i][j] =
            __builtin_amdgcn_mfma_f32_16x16x32_f16(af[i], bf[j], acc[mh * 4 + i][j], 0, 0, 0);
    __builtin_amdgcn_s_setprio(0);
  };

  stage(0);
  stage(1);
  for (int t = 0; t < NT; ++t) {
    const int slot = t & 3;
    if (t == NT - 1) {
      VMWAIT(0);
    } else {
      if constexpr (NREP == 3) VMWAIT(4); else VMWAIT(3);
    }
    __builtin_amdgcn_s_barrier();
    asm volatile("" ::: "memory");
    if (t + 2 < NT) stage((t + 2) & 3);
    const unsigned short* As = &lds[slot][0];
    const unsigned short* Bs = &lds[slot][8192];
    f16x8 bf[NREP], af0[4], af1[4];
    rdB(Bs, bf);
    rdA(As, 0, af0);
    rdA(As, 1, af1);
    mm(af0, bf, 0);
    mm(af1, bf, 1);
  }

  // epilogue
#pragma unroll
  for (int ms = 0; ms < 8; ++ms)
#pragma unroll
    for (int j = 0; j < NREP; ++j) {
      int row = m0 + wm * 128 + ms * 16 + hi * 4;
      int col = n0 + brow + j * 16 + rlo;
#pragma unroll
      for (int r = 0; r < 4; ++r) {
        float v = acc[ms][j][r];
        if constexpr (std::is_same<OUT, float>::value)
          C[(long)(row + r) * ldc + col] = v;
        else
          C[(long)(row + r) * ldc + col] = f2h_bits(v);
      }
    }
}

// ---------------- RMSNorm + RoPE + gain, scatter into Q/K layouts ----------------
__global__ __launch_bounds__(256) void qknorm_rope(const unsigned short* __restrict__ qkv,
                                                   const float* __restrict__ ctab,
                                                   const float* __restrict__ stab,
                                                   const float* __restrict__ qgain,
                                                   unsigned short* __restrict__ Qb,
                                                   unsigned short* __restrict__ Kb) {
  const int lane = threadIdx.x & 63;
  const int row = blockIdx.x * 4 + (threadIdx.x >> 6);
  const int NQROWS = BATCH * S_LEN * NH;
  const unsigned short* src;
  unsigned short* dst;
  int m, hh;
  bool isQ;
  if (row < NQROWS) {
    m = row >> 4; hh = row & 15;
    src = qkv + (long)m * 3072 + hh * HD;
    int b = m >> 11, s = m & (S_LEN - 1);
    dst = Qb + (((long)(b * NH + hh)) * S_LEN + s) * HD;
    isQ = true;
  } else {
    int rk = row - NQROWS;
    m = rk >> 2; hh = rk & 3;
    src = qkv + (long)m * 3072 + 2048 + hh * HD;
    int b = m >> 11, s = m & (S_LEN - 1);
    dst = Kb + (((long)(b * NKV + hh)) * S_LEN + s) * HD;
    isQ = false;
  }
  const int s = m & (S_LEN - 1);
  float x0 = h2f(src[lane]);
  float x1 = h2f(src[lane + 64]);
  float ss = x0 * x0 + x1 * x1;
  ss += __shfl_xor(ss, 1); ss += __shfl_xor(ss, 2); ss += __shfl_xor(ss, 4);
  ss += __shfl_xor(ss, 8); ss += __shfl_xor(ss, 16); ss += __shfl_xor(ss, 32);
  float rn = rsqrtf(ss * (1.0f / 128.0f) + 1.1920929e-07f);
  float n0 = x0 * rn, n1 = x1 * rn;
  float partner = __shfl_xor(n0, 16);
  if (lane < 32) {
    int i = lane & 15;
    float c = ctab[s * 16 + i], sn = stab[s * 16 + i];
    n0 = (lane < 16) ? (n0 * c + partner * sn) : (n0 * c - partner * sn);
  }
  if (isQ) { float g = qgain[hh]; n0 *= g; n1 *= g; }
  dst[lane] = f2h_bits(n0);
  dst[lane + 64] = f2h_bits(n1);
}

// ---------------- V transpose: qkv v-block -> Vt[b][kvh][d][s] ----------------
__global__ __launch_bounds__(256) void vtrans(const unsigned short* __restrict__ qkv,
                                              unsigned short* __restrict__ Vt) {
  int idx = blockIdx.x * 256 + threadIdx.x;
  int d = idx & 127;
  int sc = (idx >> 7) & 255;
  int kvh = (idx >> 15) & 3;
  int b = idx >> 17;
  u16x8 v;
#pragma unroll
  for (int j = 0; j < 8; ++j)
    v[j] = qkv[((long)(b * S_LEN + sc * 8 + j)) * 3072 + 2560 + kvh * HD + d];
  *reinterpret_cast<u16x8*>(Vt + (((long)(b * NKV + kvh)) * HD + d) * S_LEN + sc * 8) = v;
}

// ======== causal GQA attention (unchanged from round 10) ========
#define ATT_C3 ((float)(0.08838834764831845 * (2.0 / 30.0) * 1.4426950408889634))
#define ATT_C4 ((float)(30.0 * 1.4426950408889634))
#define ATT_C5 ((float)(60.0 * 1.4426950408889634))
#define ATT_THR ((float)(8.0 * 1.4426950408889634))

__global__ __launch_bounds__(256, 4) void attn(const unsigned short* __restrict__ Qb,
                                               const unsigned short* __restrict__ Kb,
                                               const unsigned short* __restrict__ Vt,
                                               unsigned short* __restrict__ Yb) {
  __shared__ unsigned short sm[2][8192];  // per slot: K at [0,4096), V at [4096,8192)
  const int tid = threadIdx.x, wid = tid >> 6, lane = tid & 63;
  const int gx = blockIdx.x;
  const int qq = gx >> 8;
  const int a = (gx >> 5) & 7;
  const int h = gx & 15, b = (gx >> 4) & 1;
  int qb;
  if (qq == 0) qb = 31 - a;
  else if (qq == 1) qb = 16 + a;
  else if (qq == 2) qb = 15 - a;
  else qb = a;

  const int kvh = h >> 2;
  const int rlo = lane & 15, hi = lane >> 4;
  const int q0 = qb * 64 + wid * 16;
  const unsigned short* Kp = Kb + ((long)(b * NKV + kvh)) * S_LEN * HD;
  const unsigned short* Vp = Vt + ((long)(b * NKV + kvh)) * HD * S_LEN;
  const unsigned short* Qp = Qb + (((long)(b * NH + h)) * S_LEN + q0) * HD;
  f16x8 bq[4];
#pragma unroll
  for (int dk = 0; dk < 4; ++dk) bq[dk] = ld8(Qp + rlo * HD + dk * 32 + hi * 8);

  const int kx = rlo & 7;
  const int vx = hi ^ ((rlo >> 1) & 3);
  const unsigned short* aK[4];
#pragma unroll
  for (int dk = 0; dk < 4; ++dk) aK[dk] = &sm[0][rlo * 128 + ((dk * 4 + hi) ^ kx) * 8];
  const unsigned short* aV = &sm[0][4096 + rlo * 32 + vx * 8];

  const int i0 = tid, i1 = tid + 256;
  const int rho0 = i0 >> 4, rho1 = i1 >> 4;
  auto kvperm = [](int r) { return 8 * ((r >> 2) & 3) + (r & 3) + 4 * (r >> 4); };
  const unsigned short* sK0 = Kp + (long)kvperm(rho0) * HD + ((i0 & 15) ^ (rho0 & 7)) * 8;
  const unsigned short* sK1 = Kp + (long)kvperm(rho1) * HD + ((i1 & 15) ^ (rho1 & 7)) * 8;
  const int vd0 = i0 >> 2, vd1 = i1 >> 2;
  const unsigned short* sV0 = Vp + (long)vd0 * S_LEN + ((i0 & 3) ^ ((vd0 >> 1) & 3)) * 8;
  const unsigned short* sV1 = Vp + (long)vd1 * S_LEN + ((i1 & 3) ^ ((vd1 >> 1) & 3)) * 8;
  unsigned short* dK0 = &sm[0][rho0 * 128 + (i0 & 15) * 8];
  unsigned short* dK1 = &sm[0][rho1 * 128 + (i1 & 15) * 8];
  unsigned short* dV0 = &sm[0][4096 + vd0 * 32 + (i0 & 3) * 8];
  unsigned short* dV1 = &sm[0][4096 + vd1 * 32 + (i1 & 3) * 8];

  f32x4 acc[8] = {};
  float m2c = ATT_C4 + 128.0f;
  float l_run = 0.0f;
  const int nt = 2 * qb + 2;
  const int twlast = 2 * qb + (wid >> 1);

#define STAGE(SLOT)                                                       \
  {                                                                       \
    gload_lds16(sK0, dK0 + (SLOT)*8192);                                  \
    gload_lds16(sK1, dK1 + (SLOT)*8192);                                  \
    gload_lds16(sV0, dV0 + (SLOT)*8192);                                  \
    gload_lds16(sV1, dV1 + (SLOT)*8192);                                  \
    sK0 += 4096; sK1 += 4096; sV0 += 32; sV1 += 32;                       \
  }

#define COMPUTE(T, SLOT)                                                              \
  {                                                                                   \
    f16x8 ka0[4], ka1[4];                                                             \
    _Pragma("unroll")                                                                 \
    for (int dk = 0; dk < 4; ++dk) {                                                  \
      ka0[dk] = ld8(aK[dk] + (SLOT)*8192);                                            \
      ka1[dk] = ld8(aK[dk] + (SLOT)*8192 + 2048);                                     \
    }                                                                                 \
    f32x4 s0 = {0.f, 0.f, 0.f, 0.f}, s1 = s0;                                         \
    __builtin_amdgcn_s_setprio(1);                                                    \
    _Pragma("unroll")                                                                 \
    for (int dk = 0; dk < 4; ++dk) {                                                  \
      s0 = __builtin_amdgcn_mfma_f32_16x16x32_f16(ka0[dk], bq[dk], s0, 0, 0, 0);      \
      s1 = __builtin_amdgcn_mfma_f32_16x16x32_f16(ka1[dk], bq[dk], s1, 0, 0, 0);      \
    }                                                                                 \
    __builtin_amdgcn_s_setprio(0);                                                    \
    float ea[8];                                                                      \
    _Pragma("unroll")                                                                 \
    for (int jj = 0; jj < 8; ++jj) {                                                  \
      float sc = (jj < 4) ? s0[jj] : s1[jj - 4];                                      \
      float u = __builtin_amdgcn_exp2f(sc * ATT_C3);                                  \
      float rr = __builtin_amdgcn_rcpf(u + 1.0f);                                     \
      ea[jj] = fmaf(-ATT_C5, rr, m2c);                                                \
    }                                                                                 \
    if ((T) == twlast) {                                                              \
      int qrel = q0 + rlo - 32 * (T);                                                 \
      _Pragma("unroll")                                                               \
      for (int jj = 0; jj < 8; ++jj)                                                  \
        ea[jj] = (8 * hi + jj > qrel) ? -1e30f : ea[jj];                              \
    }                                                                                 \
    float pm = ea[0];                                                                 \
    _Pragma("unroll")                                                                 \
    for (int jj = 1; jj < 8; ++jj) pm = fmaxf(pm, ea[jj]);                            \
    if (!__all(pm <= ATT_THR)) {                                                      \
      float red = fmaxf(pm, __shfl_xor(pm, 16));                                      \
      red = fmaxf(red, __shfl_xor(red, 32));                                          \
      red = fmaxf(red, 0.0f);                                                         \
      m2c -= red;                                                                     \
      float ff = __builtin_amdgcn_exp2f(-red);                                        \
      l_run *= ff;                                                                    \
      _Pragma("unroll")                                                               \
      for (int dt = 0; dt < 8; ++dt) acc[dt] *= ff;                                   \
      _Pragma("unroll")                                                               \
      for (int jj = 0; jj < 8; ++jj) ea[jj] -= red;                                   \
    }                                                                                 \
    float pv[8];                                                                      \
    _Pragma("unroll")                                                                 \
    for (int jj = 0; jj < 8; ++jj) pv[jj] = __builtin_amdgcn_exp2f(ea[jj]);           \
    l_run += ((pv[0] + pv[1]) + (pv[2] + pv[3])) + ((pv[4] + pv[5]) + (pv[6] + pv[7]));\
    u32x4 pk;                                                                         \
    pk.x = __builtin_bit_cast(unsigned int, __builtin_amdgcn_cvt_pkrtz(pv[0], pv[1]));\
    pk.y = __builtin_bit_cast(unsigned int, __builtin_amdgcn_cvt_pkrtz(pv[2], pv[3]));\
    pk.z = __builtin_bit_cast(unsigned int, __builtin_amdgcn_cvt_pkrtz(pv[4], pv[5]));\
    pk.w = __builtin_bit_cast(unsigned int, __builtin_amdgcn_cvt_pkrtz(pv[6], pv[7]));\
    f16x8 bp = __builtin_bit_cast(f16x8, pk);                                         \
    __builtin_amdgcn_s_setprio(1);                                                    \
    _Pragma("unroll")                                                                 \
    for (int g = 0; g < 2; ++g) {                                                     \
      f16x8 av[4];                                                                    \
      _Pragma("unroll")                                                               \
      for (int i = 0; i < 4; ++i) av[i] = ld8(aV + (SLOT)*8192 + (g * 4 + i) * 512);  \
      _Pragma("unroll")                                                               \
      for (int i = 0; i < 4; ++i)                                                     \
        acc[g * 4 + i] =                                                              \
            __builtin_amdgcn_mfma_f32_16x16x32_f16(av[i], bp, acc[g * 4 + i], 0, 0, 0);\
    }                                                                                 \
    __builtin_amdgcn_s_setprio(0);                                                    \
  }

  STAGE(0);  // tile 0
  for (int t = 0; t < nt; t += 2) {
    VMWAIT(0);
    __builtin_amdgcn_s_barrier();
    asm volatile("" ::: "memory");
    STAGE(1);
    if (t <= twlast) COMPUTE(t, 0);
    VMWAIT(0);
    __builtin_amdgcn_s_barrier();
    asm volatile("" ::: "memory");
    if (t + 2 < nt) STAGE(0);
    if (t + 1 <= twlast) COMPUTE(t + 1, 1);
  }
#undef STAGE
#undef COMPUTE

  float l = l_run + __shfl_xor(l_run, 16);
  l += __shfl_xor(l, 32);
  float inv = 1.0f / l;
  unsigned short* yp = Yb + ((long)(b * S_LEN + q0 + rlo)) * DIM + h * HD + 4 * hi;
#pragma unroll
  for (int dt = 0; dt < 8; ++dt) {
    u16x4 o;
#pragma unroll
    for (int r = 0; r < 4; ++r) o[r] = f2h_bits(acc[dt][r] * inv);
    *reinterpret_cast<u16x4*>(yp + dt * 16) = o;
  }
}

extern "C" void kernel_launch(void* const* d_in, const int* in_sizes, int n_in,
                              void* d_out, int out_size, void* d_ws, size_t ws_size,
                              hipStream_t stream) {
  const float* x = (const float*)d_in[0];
  const float* Wq = (const float*)d_in[1];
  const float* Wk = (const float*)d_in[2];
  const float* Wv = (const float*)d_in[3];
  const float* Wp = (const float*)d_in[4];
  const float* qg = (const float*)d_in[5];
  float* out = (float*)d_out;

  char* ws = (char*)d_ws;
  size_t off = 0;
  auto alloc = [&](size_t bytes) {
    char* p = ws + off;
    off += (bytes + 255) & ~(size_t)255;
    return p;
  };
  unsigned short* xb   = (unsigned short*)alloc(8388608ull * 2);
  unsigned short* wqkv = (unsigned short*)alloc(6291456ull * 2);
  unsigned short* wpj  = (unsigned short*)alloc(4194304ull * 2);
  unsigned short* qkv  = (unsigned short*)alloc(4096ull * 3072 * 2);
  unsigned short* Qbuf = (unsigned short*)alloc(8388608ull * 2);
  unsigned short* Kb   = (unsigned short*)alloc(2097152ull * 2);
  unsigned short* Vt   = (unsigned short*)alloc(2097152ull * 2);
  unsigned short* Yb   = (unsigned short*)alloc(8388608ull * 2);
  float* ctab = (float*)alloc(32768ull * 4);
  float* stab = (float*)alloc(32768ull * 4);

  cvt_all<<<18432, 256, 0, stream>>>(x, Wq, Wk, Wv, Wp, xb, wqkv, wpj);
  rope_tables<<<128, 256, 0, stream>>>(ctab, stab);

  // qkv = x @ [Wq;Wk;Wv]^T : M=4096 N=3072 K=2048  (256x192 tiles -> 256 blocks)
  gemm_pl<3, unsigned short><<<dim3(16, 16), 512, 0, stream>>>(xb, wqkv, qkv, 2048, 3072);

  qknorm_rope<<<(BATCH * S_LEN * (NH + NKV)) / 4, 256, 0, stream>>>(qkv, ctab, stab, qg, Qbuf, Kb);
  vtrans<<<(BATCH * NKV * HD * (S_LEN / 8)) / 256, 256, 0, stream>>>(qkv, Vt);

  attn<<<1024, 256, 0, stream>>>(Qbuf, Kb, Vt, Yb);

  // out = y @ Wproj^T : M=4096 N=2048 K=2048  (256x128 tiles -> 256 blocks)
  gemm_pl<2, float><<<dim3(16, 16), 512, 0, stream>>>(Yb, wpj, out, 2048, 2048);
}